// Round 5
// baseline (414.224 us; speedup 1.0000x reference)
//
#include <hip/hip_runtime.h>
#include <hip/hip_bf16.h>

#define DIM 1024
#define TPB 8   // tokens per block

typedef int   i32x4 __attribute__((ext_vector_type(4)));
typedef float f32x4 __attribute__((ext_vector_type(4)));

__global__ __launch_bounds__(256) void emb_gather_kernel(
    const int* __restrict__ input_ids,   // (B*S)
    const int* __restrict__ base_idx,    // (V, D)
    const int* __restrict__ fine_idx,    // (V, D)
    const float* __restrict__ lut,       // (65536)
    float* __restrict__ out,             // (B*S, D)
    int n_tokens)
{
    const int t0 = blockIdx.x * TPB;
    const int d0 = threadIdx.x << 2;                 // 256 threads * 4 = 1024

    // Phase 1: all token ids (wave-uniform scalar loads)
    int ids[TPB];
#pragma unroll
    for (int t = 0; t < TPB; ++t) {
        int tok = t0 + t;
        ids[t] = (tok < n_tokens) ? input_ids[tok] : 0;
    }

    // Phase 2: issue ALL index-row loads back-to-back (16 independent 16B
    // loads per lane in flight -> hides ~900cy HBM latency)
    i32x4 b[TPB], f[TPB];
#pragma unroll
    for (int t = 0; t < TPB; ++t) {
        const long long rowoff = (long long)ids[t] * DIM + d0;
        b[t] = *reinterpret_cast<const i32x4*>(base_idx + rowoff);
        f[t] = *reinterpret_cast<const i32x4*>(fine_idx + rowoff);
    }

    // Phase 3: lut lookups (L2-resident, scattered) + streaming store
#pragma unroll
    for (int t = 0; t < TPB; ++t) {
        int tok = t0 + t;
        if (tok >= n_tokens) continue;
        f32x4 o;
        o.x = lut[(b[t].x << 8) + f[t].x];
        o.y = lut[(b[t].y << 8) + f[t].y];
        o.z = lut[(b[t].z << 8) + f[t].z];
        o.w = lut[(b[t].w << 8) + f[t].w];
        __builtin_nontemporal_store(o, reinterpret_cast<f32x4*>(out + (long long)tok * DIM + d0));
    }
}

extern "C" void kernel_launch(void* const* d_in, const int* in_sizes, int n_in,
                              void* d_out, int out_size, void* d_ws, size_t ws_size,
                              hipStream_t stream)
{
    const int*   input_ids = (const int*)d_in[0];
    const int*   base_idx  = (const int*)d_in[1];
    const int*   fine_idx  = (const int*)d_in[2];
    const float* lut       = (const float*)d_in[3];
    float*       out       = (float*)d_out;

    const int n_tokens = in_sizes[0];                // B*S = 16384

    const int n_blocks = (n_tokens + TPB - 1) / TPB; // 2048
    emb_gather_kernel<<<dim3(n_blocks), dim3(256), 0, stream>>>(
        input_ids, base_idx, fine_idx, lut, out, n_tokens);
}

// Round 6
// 408.383 us; speedup vs baseline: 1.0143x; 1.0143x over previous
//
#include <hip/hip_runtime.h>
#include <hip/hip_bf16.h>

#define DIM 1024
#define TPB 8   // tokens per block

typedef int   i32x4 __attribute__((ext_vector_type(4)));
typedef float f32x4 __attribute__((ext_vector_type(4)));

__global__ __launch_bounds__(256) void emb_gather_kernel(
    const int* __restrict__ input_ids,   // (B*S)
    const int* __restrict__ base_idx,    // (V, D)
    const int* __restrict__ fine_idx,    // (V, D)
    const float* __restrict__ lut,       // (65536)
    float* __restrict__ out,             // (B*S, D)
    int n_tokens)
{
    const int t0 = blockIdx.x * TPB;
    const int d0 = threadIdx.x << 2;                 // 256 threads * 4 = 1024

    // Phase 1: all token ids (wave-uniform scalar loads)
    int ids[TPB];
#pragma unroll
    for (int t = 0; t < TPB; ++t) {
        int tok = t0 + t;
        ids[t] = (tok < n_tokens) ? input_ids[tok] : 0;
    }

    // Phase 2: issue ALL index-row loads back-to-back (16 independent 16B
    // loads per lane in flight -> hides ~900cy HBM latency).
    // Nontemporal: rows are ~85% single-use; don't evict the hot 256KB lut
    // (or duplicate-token rows) from L2/L3.
    i32x4 b[TPB], f[TPB];
#pragma unroll
    for (int t = 0; t < TPB; ++t) {
        const long long rowoff = (long long)ids[t] * DIM + d0;
        b[t] = __builtin_nontemporal_load(reinterpret_cast<const i32x4*>(base_idx + rowoff));
        f[t] = __builtin_nontemporal_load(reinterpret_cast<const i32x4*>(fine_idx + rowoff));
    }

    // Phase 3: lut lookups (L2-resident, scattered) + streaming store
#pragma unroll
    for (int t = 0; t < TPB; ++t) {
        int tok = t0 + t;
        if (tok >= n_tokens) continue;
        f32x4 o;
        o.x = lut[(b[t].x << 8) + f[t].x];
        o.y = lut[(b[t].y << 8) + f[t].y];
        o.z = lut[(b[t].z << 8) + f[t].z];
        o.w = lut[(b[t].w << 8) + f[t].w];
        __builtin_nontemporal_store(o, reinterpret_cast<f32x4*>(out + (long long)tok * DIM + d0));
    }
}

extern "C" void kernel_launch(void* const* d_in, const int* in_sizes, int n_in,
                              void* d_out, int out_size, void* d_ws, size_t ws_size,
                              hipStream_t stream)
{
    const int*   input_ids = (const int*)d_in[0];
    const int*   base_idx  = (const int*)d_in[1];
    const int*   fine_idx  = (const int*)d_in[2];
    const float* lut       = (const float*)d_in[3];
    float*       out       = (float*)d_out;

    const int n_tokens = in_sizes[0];                // B*S = 16384

    const int n_blocks = (n_tokens + TPB - 1) / TPB; // 2048
    emb_gather_kernel<<<dim3(n_blocks), dim3(256), 0, stream>>>(
        input_ids, base_idx, fine_idx, lut, out, n_tokens);
}